// Round 3
// baseline (229.386 us; speedup 1.0000x reference)
//
#include <hip/hip_runtime.h>

typedef __attribute__((ext_vector_type(8))) short  short8;
typedef __attribute__((ext_vector_type(4))) float  floatx4;
typedef __attribute__((ext_vector_type(4))) int    intx4;

constexpr int DIN = 100;
constexpr int H   = 64;
constexpr int G   = 10;
constexpr int NH  = 5;
constexpr int MWG = 128;                 // rows per block (4 waves x 32 rows)
constexpr int HP  = 72;                  // hbuf pitch in halfwords: 144B rows, 16B-aligned

// fragment counts in ws: dW0 (K=128 padded) 16; dW1 8; dbW 2; W0 5h*8=40
constexpr int NF_DW0 = 16, NF_DW1 = 8, NF_DBW = 2;
constexpr int NF_LIN = NF_DW0 + NF_DW1 + NF_DBW;     // 26
constexpr int NF_TOT = NF_LIN + 40;                  // 66

__device__ __forceinline__ unsigned short f2bf_rne(float f) {
    union { float f; unsigned u; } v{f};
    unsigned r = v.u + 0x7FFF + ((v.u >> 16) & 1);   // RNE
    return (unsigned short)(r >> 16);
}

// round-half-up pack of 8 floats -> short8 (bf16); ~2.5 VALU ops/value
__device__ __forceinline__ short8 pack8(const float* f) {
    intx4 p;
    #pragma unroll
    for (int j = 0; j < 4; ++j) {
        unsigned a = __float_as_uint(f[2 * j])     + 0x8000u;
        unsigned b = __float_as_uint(f[2 * j + 1]) + 0x8000u;
        p[j] = (int)((b & 0xFFFF0000u) | (a >> 16));
    }
    union { intx4 i; short8 s; } u; u.i = p;
    return u.s;
}

__device__ __forceinline__ unsigned short f2bf_hu(float f) {
    return (unsigned short)((__float_as_uint(f) + 0x8000u) >> 16);
}

__device__ __forceinline__ short8 ldfrag(const unsigned short* __restrict__ ws,
                                         int f, int lane) {
    return *(const short8*)(ws + (size_t)(f * 64 + lane) * 8);
}

// ---- pre-kernel: pack all weights as bf16 MFMA B-fragments into ws ----
// B-frag layout (16x16x32): lane holds B[k = (lane>>4)*8 + j][n = lane&15]
__global__ __launch_bounds__(64) void pack_kernel(
    const float* __restrict__ dW0, const float* __restrict__ dW1,
    const float* __restrict__ dbW, const float* __restrict__ W0,
    unsigned short* __restrict__ ws)
{
    const int f = blockIdx.x;            // fragment id 0..65
    const int lane = threadIdx.x;
    const int q = lane >> 4, cl = lane & 15;
    float v[8];
    if (f < NF_DW0) {                    // dW0: K padded 100->128 with zeros
        int c = f >> 2, g = f & 3;
        #pragma unroll
        for (int j = 0; j < 8; ++j) {
            int k = c * 32 + q * 8 + j, n = g * 16 + cl;
            v[j] = (k < DIN) ? dW0[k * H + n] : 0.0f;
        }
    } else if (f < NF_DW0 + NF_DW1) {    // dW1: K=64
        int r = f - NF_DW0; int c = r >> 2, g = r & 3;
        #pragma unroll
        for (int j = 0; j < 8; ++j) {
            int k = c * 32 + q * 8 + j, n = g * 16 + cl;
            v[j] = dW1[k * H + n];
        }
    } else if (f < NF_LIN) {             // dbW: K=64, N=11 padded to 16
        int c = f - (NF_DW0 + NF_DW1);
        #pragma unroll
        for (int j = 0; j < 8; ++j) {
            int k = c * 32 + q * 8 + j, n = cl;
            v[j] = (n <= G) ? dbW[k * (G + 1) + n] : 0.0f;
        }
    } else {                             // W0: 5 heads, K=64
        int r = f - NF_LIN; int h = r >> 3; r &= 7; int c = r >> 2, g = r & 3;
        #pragma unroll
        for (int j = 0; j < 8; ++j) {
            int k = c * 32 + q * 8 + j, n = g * 16 + cl;
            v[j] = W0[(h * H + k) * H + n];
        }
    }
    short8 s;
    #pragma unroll
    for (int j = 0; j < 8; ++j) s[j] = (short)f2bf_rne(v[j]);
    *(short8*)(ws + (size_t)(f * 64 + lane) * 8) = s;
}

// ---- main kernel: no barriers, wave-private hbuf slices, global B-frags ----
__global__ __launch_bounds__(256) void drnet_mfma(
    const float* __restrict__ dosage, const float* __restrict__ x,
    const float* __restrict__ db0, const float* __restrict__ db1,
    const float* __restrict__ dbB,
    const float* __restrict__ tw0, const float* __restrict__ b0,
    const float* __restrict__ W1, const float* __restrict__ tw1,
    const float* __restrict__ b1,
    const unsigned short* __restrict__ wsfrag,
    float* __restrict__ outg, float* __restrict__ outq)
{
    __shared__ unsigned short hbuf[MWG * HP];    // 18432 B
    const int tid  = threadIdx.x;
    const int wave = tid >> 6, lane = tid & 63;
    const int q = lane >> 4, cl = lane & 15;
    const int rowbase = blockIdx.x * MWG + wave * 32;   // this wave's 32 rows
    unsigned short* hb = hbuf + wave * 32 * HP;

    // dosage + bucket for my 8 C-layout rows
    float t8[2][4];
    int   bk8[2][4];
    #pragma unroll
    for (int mt = 0; mt < 2; ++mt)
        #pragma unroll
        for (int r = 0; r < 4; ++r) {
            float t = dosage[rowbase + mt * 16 + 4 * q + r];
            t8[mt][r] = t;
            int bk = (int)floorf(t * (float)NH);
            bk8[mt][r] = min(max(bk, 0), NH - 1);
        }

    floatx4 acc[2][4];

    // ================= layer 1: h1 = relu(x @ dW0 + db0) =================
    short8 a1[2][4];
    #pragma unroll
    for (int mt = 0; mt < 2; ++mt) {
        const float* xr = x + (size_t)(rowbase + mt * 16 + cl) * DIN;
        #pragma unroll
        for (int cch = 0; cch < 4; ++cch) {
            float f[8];
            if (cch < 3) {
                floatx4 u0 = *(const floatx4*)(xr + cch * 32 + q * 8);
                floatx4 u1 = *(const floatx4*)(xr + cch * 32 + q * 8 + 4);
                f[0]=u0.x; f[1]=u0.y; f[2]=u0.z; f[3]=u0.w;
                f[4]=u1.x; f[5]=u1.y; f[6]=u1.z; f[7]=u1.w;
            } else {
                if (q == 0) {
                    floatx4 u0 = *(const floatx4*)(xr + 96);
                    f[0]=u0.x; f[1]=u0.y; f[2]=u0.z; f[3]=u0.w;
                    f[4]=f[5]=f[6]=f[7]=0.0f;
                } else {
                    #pragma unroll
                    for (int j = 0; j < 8; ++j) f[j] = 0.0f;
                }
            }
            a1[mt][cch] = pack8(f);
        }
    }
    #pragma unroll
    for (int mt = 0; mt < 2; ++mt)
        #pragma unroll
        for (int g = 0; g < 4; ++g) acc[mt][g] = (floatx4)0.0f;
    #pragma unroll
    for (int cch = 0; cch < 4; ++cch)
        #pragma unroll
        for (int g = 0; g < 4; ++g) {
            short8 bf = ldfrag(wsfrag, cch * 4 + g, lane);
            #pragma unroll
            for (int mt = 0; mt < 2; ++mt)
                acc[mt][g] = __builtin_amdgcn_mfma_f32_16x16x32_bf16(a1[mt][cch], bf, acc[mt][g], 0, 0, 0);
        }
    #pragma unroll
    for (int g = 0; g < 4; ++g) {
        float bias = db0[g * 16 + cl];
        #pragma unroll
        for (int mt = 0; mt < 2; ++mt)
            #pragma unroll
            for (int r = 0; r < 4; ++r)
                hb[(mt * 16 + 4 * q + r) * HP + g * 16 + cl] =
                    f2bf_hu(fmaxf(acc[mt][g][r] + bias, 0.0f));
    }

    // ================= layer 2: h2 = relu(h1 @ dW1 + db1) =================
    short8 a2[2][2];
    #pragma unroll
    for (int mt = 0; mt < 2; ++mt)
        #pragma unroll
        for (int cch = 0; cch < 2; ++cch)
            a2[mt][cch] = *(const short8*)(hb + (mt * 16 + cl) * HP + cch * 32 + q * 8);
    #pragma unroll
    for (int mt = 0; mt < 2; ++mt)
        #pragma unroll
        for (int g = 0; g < 4; ++g) acc[mt][g] = (floatx4)0.0f;
    #pragma unroll
    for (int cch = 0; cch < 2; ++cch)
        #pragma unroll
        for (int g = 0; g < 4; ++g) {
            short8 bf = ldfrag(wsfrag, NF_DW0 + cch * 4 + g, lane);
            #pragma unroll
            for (int mt = 0; mt < 2; ++mt)
                acc[mt][g] = __builtin_amdgcn_mfma_f32_16x16x32_bf16(a2[mt][cch], bf, acc[mt][g], 0, 0, 0);
        }
    #pragma unroll
    for (int g = 0; g < 4; ++g) {
        float bias = db1[g * 16 + cl];
        #pragma unroll
        for (int mt = 0; mt < 2; ++mt)
            #pragma unroll
            for (int r = 0; r < 4; ++r)
                hb[(mt * 16 + 4 * q + r) * HP + g * 16 + cl] =
                    f2bf_hu(fmaxf(acc[mt][g][r] + bias, 0.0f));
    }

    // h2 A-fragments (reused by density + all heads)
    short8 af[2][2];
    #pragma unroll
    for (int mt = 0; mt < 2; ++mt)
        #pragma unroll
        for (int cch = 0; cch < 2; ++cch)
            af[mt][cch] = *(const short8*)(hb + (mt * 16 + cl) * HP + cch * 32 + q * 8);

    // ================= density: softmax(h2 @ dbW + dbB) + interp =================
    floatx4 accd[2];
    accd[0] = (floatx4)0.0f; accd[1] = (floatx4)0.0f;
    #pragma unroll
    for (int cch = 0; cch < 2; ++cch) {
        short8 bf = ldfrag(wsfrag, NF_DW0 + NF_DW1 + cch, lane);
        #pragma unroll
        for (int mt = 0; mt < 2; ++mt)
            accd[mt] = __builtin_amdgcn_mfma_f32_16x16x32_bf16(af[mt][cch], bf, accd[mt], 0, 0, 0);
    }
    const float dbBv = (cl <= G) ? dbB[cl] : 0.0f;
    float gout[2][4];
    #pragma unroll
    for (int mt = 0; mt < 2; ++mt)
        #pragma unroll
        for (int r = 0; r < 4; ++r) {
            float l = (cl <= G) ? (accd[mt][r] + dbBv) : -1e30f;
            float m = l;
            m = fmaxf(m, __shfl_xor(m, 1)); m = fmaxf(m, __shfl_xor(m, 2));
            m = fmaxf(m, __shfl_xor(m, 4)); m = fmaxf(m, __shfl_xor(m, 8));
            float e = __expf(l - m);
            float s = e;
            s += __shfl_xor(s, 1); s += __shfl_xor(s, 2);
            s += __shfl_xor(s, 4); s += __shfl_xor(s, 8);
            const float t  = t8[mt][r];
            const float tB = t * (float)G;
            const float U  = ceilf(tB);
            const float inter = 1.0f - (U - tB);
            int Ui = (int)U; int Li = Ui - 1; if (Li < 0) Li = 0;
            float pL = __shfl(e, q * 16 + Li);
            float pU = __shfl(e, q * 16 + Ui);
            gout[mt][r] = (pL + (pU - pL) * inter) / s;
        }
    if (cl == 0) {
        #pragma unroll
        for (int mt = 0; mt < 2; ++mt) {
            floatx4 gv = { gout[mt][0], gout[mt][1], gout[mt][2], gout[mt][3] };
            *(floatx4*)(outg + rowbase + mt * 16 + 4 * q) = gv;
        }
    }

    // ================= heads: MFMA all 5, cndmask-select per row =================
    float asel[2][4][4];
    #pragma unroll
    for (int mt = 0; mt < 2; ++mt)
        #pragma unroll
        for (int g = 0; g < 4; ++g)
            #pragma unroll
            for (int r = 0; r < 4; ++r) asel[mt][g][r] = 0.0f;

    #pragma unroll 1
    for (int h = 0; h < NH; ++h) {
        floatx4 acch[2][4];
        #pragma unroll
        for (int mt = 0; mt < 2; ++mt)
            #pragma unroll
            for (int g = 0; g < 4; ++g) acch[mt][g] = (floatx4)0.0f;
        #pragma unroll
        for (int cch = 0; cch < 2; ++cch)
            #pragma unroll
            for (int g = 0; g < 4; ++g) {
                short8 bf = ldfrag(wsfrag, NF_LIN + h * 8 + cch * 4 + g, lane);
                #pragma unroll
                for (int mt = 0; mt < 2; ++mt)
                    acch[mt][g] = __builtin_amdgcn_mfma_f32_16x16x32_bf16(af[mt][cch], bf, acch[mt][g], 0, 0, 0);
            }
        #pragma unroll
        for (int mt = 0; mt < 2; ++mt)
            #pragma unroll
            for (int r = 0; r < 4; ++r) {
                bool sel = (bk8[mt][r] == h);
                #pragma unroll
                for (int g = 0; g < 4; ++g)
                    asel[mt][g][r] = sel ? acch[mt][g][r] : asel[mt][g][r];
            }
    }

    // gathered epilogue: h0 = asel + t*tw0[bk] + b0[bk]; q += relu(h0)*W1[bk]
    float qp[2][4] = {{0,0,0,0},{0,0,0,0}};
    #pragma unroll
    for (int g = 0; g < 4; ++g) {
        const int ci = g * 16 + cl;
        #pragma unroll
        for (int mt = 0; mt < 2; ++mt)
            #pragma unroll
            for (int r = 0; r < 4; ++r) {
                const int off = bk8[mt][r] * H + ci;
                float h0 = asel[mt][g][r] + t8[mt][r] * tw0[off] + b0[off];
                qp[mt][r] += fmaxf(h0, 0.0f) * W1[off];
            }
    }
    #pragma unroll
    for (int mt = 0; mt < 2; ++mt)
        #pragma unroll
        for (int r = 0; r < 4; ++r) {
            float s = qp[mt][r];
            s += __shfl_xor(s, 1); s += __shfl_xor(s, 2);
            s += __shfl_xor(s, 4); s += __shfl_xor(s, 8);
            const int h = bk8[mt][r];
            qp[mt][r] = s + t8[mt][r] * tw1[h] + b1[h];
        }
    if (cl == 0) {
        #pragma unroll
        for (int mt = 0; mt < 2; ++mt) {
            floatx4 Qv = { qp[mt][0], qp[mt][1], qp[mt][2], qp[mt][3] };
            *(floatx4*)(outq + rowbase + mt * 16 + 4 * q) = Qv;
        }
    }
}

extern "C" void kernel_launch(void* const* d_in, const int* in_sizes, int n_in,
                              void* d_out, int out_size, void* d_ws, size_t ws_size,
                              hipStream_t stream) {
    const float* dosage = (const float*)d_in[0];
    const float* x      = (const float*)d_in[1];
    const float* dW0    = (const float*)d_in[2];
    const float* db0    = (const float*)d_in[3];
    const float* dW1    = (const float*)d_in[4];
    const float* db1    = (const float*)d_in[5];
    const float* dbW    = (const float*)d_in[6];
    const float* dbB    = (const float*)d_in[7];
    const float* W0     = (const float*)d_in[8];
    const float* tw0    = (const float*)d_in[9];
    const float* b0     = (const float*)d_in[10];
    const float* W1     = (const float*)d_in[11];
    const float* tw1    = (const float*)d_in[12];
    const float* b1     = (const float*)d_in[13];

    const int Btot = in_sizes[0];
    float* outg = (float*)d_out;
    float* outq = outg + Btot;
    unsigned short* ws = (unsigned short*)d_ws;

    pack_kernel<<<NF_TOT, 64, 0, stream>>>(dW0, dW1, dbW, W0, ws);
    drnet_mfma<<<Btot / MWG, 256, 0, stream>>>(dosage, x, db0, db1, dbB,
                                               tw0, b0, W1, tw1, b1,
                                               ws, outg, outq);
}

// Round 4
// 210.354 us; speedup vs baseline: 1.0905x; 1.0905x over previous
//
#include <hip/hip_runtime.h>

typedef __attribute__((ext_vector_type(8))) short  short8;
typedef __attribute__((ext_vector_type(4))) float  floatx4;
typedef __attribute__((ext_vector_type(4))) int    intx4;

constexpr int DIN = 100;
constexpr int H   = 64;
constexpr int G   = 10;
constexpr int NH  = 5;
constexpr int MWG = 64;                  // rows per block (4 waves x 16 rows)
constexpr int HP  = 72;                  // hbuf pitch in halfwords: 144B rows, 16B-aligned

// fragment counts in ws: dW0 (K=128 padded) 16; dW1 8; dbW 2; W0 5h*8=40
constexpr int NF_DW0 = 16, NF_DW1 = 8, NF_DBW = 2;
constexpr int NF_LIN = NF_DW0 + NF_DW1 + NF_DBW;     // 26
constexpr int NF_TOT = NF_LIN + 40;                  // 66

__device__ __forceinline__ unsigned short f2bf_rne(float f) {
    union { float f; unsigned u; } v{f};
    unsigned r = v.u + 0x7FFF + ((v.u >> 16) & 1);   // RNE
    return (unsigned short)(r >> 16);
}

// round-half-up pack of 8 floats -> short8 (bf16); ~2.5 VALU ops/value
__device__ __forceinline__ short8 pack8(const float* f) {
    intx4 p;
    #pragma unroll
    for (int j = 0; j < 4; ++j) {
        unsigned a = __float_as_uint(f[2 * j])     + 0x8000u;
        unsigned b = __float_as_uint(f[2 * j + 1]) + 0x8000u;
        p[j] = (int)((b & 0xFFFF0000u) | (a >> 16));
    }
    union { intx4 i; short8 s; } u; u.i = p;
    return u.s;
}

__device__ __forceinline__ unsigned short f2bf_hu(float f) {
    return (unsigned short)((__float_as_uint(f) + 0x8000u) >> 16);
}

__device__ __forceinline__ short8 ldfrag(const unsigned short* __restrict__ ws,
                                         int f, int lane) {
    return *(const short8*)(ws + (size_t)(f * 64 + lane) * 8);
}

// ---- pre-kernel: pack all weights as bf16 MFMA B-fragments into ws ----
// B-frag layout (16x16x32): lane holds B[k = (lane>>4)*8 + j][n = lane&15]
__global__ __launch_bounds__(64) void pack_kernel(
    const float* __restrict__ dW0, const float* __restrict__ dW1,
    const float* __restrict__ dbW, const float* __restrict__ W0,
    unsigned short* __restrict__ ws)
{
    const int f = blockIdx.x;            // fragment id 0..65
    const int lane = threadIdx.x;
    const int q = lane >> 4, cl = lane & 15;
    float v[8];
    if (f < NF_DW0) {                    // dW0: K padded 100->128 with zeros
        int c = f >> 2, g = f & 3;
        #pragma unroll
        for (int j = 0; j < 8; ++j) {
            int k = c * 32 + q * 8 + j, n = g * 16 + cl;
            v[j] = (k < DIN) ? dW0[k * H + n] : 0.0f;
        }
    } else if (f < NF_DW0 + NF_DW1) {    // dW1: K=64
        int r = f - NF_DW0; int c = r >> 2, g = r & 3;
        #pragma unroll
        for (int j = 0; j < 8; ++j) {
            int k = c * 32 + q * 8 + j, n = g * 16 + cl;
            v[j] = dW1[k * H + n];
        }
    } else if (f < NF_LIN) {             // dbW: K=64, N=11 padded to 16
        int c = f - (NF_DW0 + NF_DW1);
        #pragma unroll
        for (int j = 0; j < 8; ++j) {
            int k = c * 32 + q * 8 + j, n = cl;
            v[j] = (n <= G) ? dbW[k * (G + 1) + n] : 0.0f;
        }
    } else {                             // W0: 5 heads, K=64
        int r = f - NF_LIN; int h = r >> 3; r &= 7; int c = r >> 2, g = r & 3;
        #pragma unroll
        for (int j = 0; j < 8; ++j) {
            int k = c * 32 + q * 8 + j, n = g * 16 + cl;
            v[j] = W0[(h * H + k) * H + n];
        }
    }
    short8 s;
    #pragma unroll
    for (int j = 0; j < 8; ++j) s[j] = (short)f2bf_rne(v[j]);
    *(short8*)(ws + (size_t)(f * 64 + lane) * 8) = s;
}

// ---- main kernel: 16 rows/wave, no barriers, regs <=128 for 16 waves/CU ----
__global__ __launch_bounds__(256, 4) void drnet_mfma(
    const float* __restrict__ dosage, const float* __restrict__ x,
    const float* __restrict__ db0, const float* __restrict__ db1,
    const float* __restrict__ dbB,
    const float* __restrict__ tw0, const float* __restrict__ b0,
    const float* __restrict__ W1, const float* __restrict__ tw1,
    const float* __restrict__ b1,
    const unsigned short* __restrict__ wsfrag,
    float* __restrict__ outg, float* __restrict__ outq)
{
    __shared__ unsigned short hbuf[MWG * HP];    // 9216 B
    const int tid  = threadIdx.x;
    const int wave = tid >> 6, lane = tid & 63;
    const int q = lane >> 4, cl = lane & 15;
    const int rowbase = blockIdx.x * MWG + wave * 16;   // this wave's 16 rows
    unsigned short* hb = hbuf + wave * 16 * HP;

    // dosage + bucket for my 4 C-layout rows (rows 4q+r)
    float t4[4];
    int   bk4[4];
    #pragma unroll
    for (int r = 0; r < 4; ++r) {
        float t = dosage[rowbase + 4 * q + r];
        t4[r] = t;
        int bk = (int)floorf(t * (float)NH);
        bk4[r] = min(max(bk, 0), NH - 1);
    }

    floatx4 acc[4];

    // ================= layer 1: h1 = relu(x @ dW0 + db0) =================
    short8 a1[4];
    {
        const float* xr = x + (size_t)(rowbase + cl) * DIN;
        #pragma unroll
        for (int cch = 0; cch < 4; ++cch) {
            float f[8];
            if (cch < 3) {
                floatx4 u0 = *(const floatx4*)(xr + cch * 32 + q * 8);
                floatx4 u1 = *(const floatx4*)(xr + cch * 32 + q * 8 + 4);
                f[0]=u0.x; f[1]=u0.y; f[2]=u0.z; f[3]=u0.w;
                f[4]=u1.x; f[5]=u1.y; f[6]=u1.z; f[7]=u1.w;
            } else {
                if (q == 0) {
                    floatx4 u0 = *(const floatx4*)(xr + 96);
                    f[0]=u0.x; f[1]=u0.y; f[2]=u0.z; f[3]=u0.w;
                    f[4]=f[5]=f[6]=f[7]=0.0f;
                } else {
                    #pragma unroll
                    for (int j = 0; j < 8; ++j) f[j] = 0.0f;
                }
            }
            a1[cch] = pack8(f);
        }
    }
    #pragma unroll
    for (int g = 0; g < 4; ++g) acc[g] = (floatx4)0.0f;
    #pragma unroll
    for (int cch = 0; cch < 4; ++cch)
        #pragma unroll
        for (int g = 0; g < 4; ++g) {
            short8 bf = ldfrag(wsfrag, cch * 4 + g, lane);
            acc[g] = __builtin_amdgcn_mfma_f32_16x16x32_bf16(a1[cch], bf, acc[g], 0, 0, 0);
        }
    #pragma unroll
    for (int g = 0; g < 4; ++g) {
        float bias = db0[g * 16 + cl];
        #pragma unroll
        for (int r = 0; r < 4; ++r)
            hb[(4 * q + r) * HP + g * 16 + cl] =
                f2bf_hu(fmaxf(acc[g][r] + bias, 0.0f));
    }
    // wave-private rows + in-order DS pipe: no barrier needed

    // ================= layer 2: h2 = relu(h1 @ dW1 + db1) =================
    short8 a2[2];
    #pragma unroll
    for (int cch = 0; cch < 2; ++cch)
        a2[cch] = *(const short8*)(hb + cl * HP + cch * 32 + q * 8);
    #pragma unroll
    for (int g = 0; g < 4; ++g) acc[g] = (floatx4)0.0f;
    #pragma unroll
    for (int cch = 0; cch < 2; ++cch)
        #pragma unroll
        for (int g = 0; g < 4; ++g) {
            short8 bf = ldfrag(wsfrag, NF_DW0 + cch * 4 + g, lane);
            acc[g] = __builtin_amdgcn_mfma_f32_16x16x32_bf16(a2[cch], bf, acc[g], 0, 0, 0);
        }
    #pragma unroll
    for (int g = 0; g < 4; ++g) {
        float bias = db1[g * 16 + cl];
        #pragma unroll
        for (int r = 0; r < 4; ++r)
            hb[(4 * q + r) * HP + g * 16 + cl] =
                f2bf_hu(fmaxf(acc[g][r] + bias, 0.0f));
    }

    // h2 A-fragments (reused by density + all heads)
    short8 af[2];
    #pragma unroll
    for (int cch = 0; cch < 2; ++cch)
        af[cch] = *(const short8*)(hb + cl * HP + cch * 32 + q * 8);

    // ================= density: softmax(h2 @ dbW + dbB) + interp =================
    floatx4 accd = (floatx4)0.0f;
    #pragma unroll
    for (int cch = 0; cch < 2; ++cch) {
        short8 bf = ldfrag(wsfrag, NF_DW0 + NF_DW1 + cch, lane);
        accd = __builtin_amdgcn_mfma_f32_16x16x32_bf16(af[cch], bf, accd, 0, 0, 0);
    }
    const float dbBv = (cl <= G) ? dbB[cl] : 0.0f;
    float gout[4];
    #pragma unroll
    for (int r = 0; r < 4; ++r) {
        float l = (cl <= G) ? (accd[r] + dbBv) : -1e30f;
        float m = l;
        m = fmaxf(m, __shfl_xor(m, 1)); m = fmaxf(m, __shfl_xor(m, 2));
        m = fmaxf(m, __shfl_xor(m, 4)); m = fmaxf(m, __shfl_xor(m, 8));
        float e = __expf(l - m);
        float s = e;
        s += __shfl_xor(s, 1); s += __shfl_xor(s, 2);
        s += __shfl_xor(s, 4); s += __shfl_xor(s, 8);
        const float t  = t4[r];
        const float tB = t * (float)G;
        const float U  = ceilf(tB);
        const float inter = 1.0f - (U - tB);
        int Ui = (int)U; int Li = Ui - 1; if (Li < 0) Li = 0;
        float pL = __shfl(e, q * 16 + Li);
        float pU = __shfl(e, q * 16 + Ui);
        gout[r] = (pL + (pU - pL) * inter) / s;
    }
    if (cl == 0) {
        floatx4 gv = { gout[0], gout[1], gout[2], gout[3] };
        *(floatx4*)(outg + rowbase + 4 * q) = gv;
    }

    // ================= heads: MFMA all 5, cndmask-select per row =================
    float asel[4][4];
    #pragma unroll
    for (int g = 0; g < 4; ++g)
        #pragma unroll
        for (int r = 0; r < 4; ++r) asel[g][r] = 0.0f;

    #pragma unroll 1
    for (int h = 0; h < NH; ++h) {
        floatx4 acch[4];
        #pragma unroll
        for (int g = 0; g < 4; ++g) acch[g] = (floatx4)0.0f;
        #pragma unroll
        for (int cch = 0; cch < 2; ++cch)
            #pragma unroll
            for (int g = 0; g < 4; ++g) {
                short8 bf = ldfrag(wsfrag, NF_LIN + h * 8 + cch * 4 + g, lane);
                acch[g] = __builtin_amdgcn_mfma_f32_16x16x32_bf16(af[cch], bf, acch[g], 0, 0, 0);
            }
        #pragma unroll
        for (int r = 0; r < 4; ++r) {
            bool sel = (bk4[r] == h);
            #pragma unroll
            for (int g = 0; g < 4; ++g)
                asel[g][r] = sel ? acch[g][r] : asel[g][r];
        }
    }

    // gathered epilogue: h0 = asel + t*tw0[bk] + b0[bk]; q += relu(h0)*W1[bk]
    float qp[4] = {0, 0, 0, 0};
    #pragma unroll
    for (int g = 0; g < 4; ++g) {
        const int ci = g * 16 + cl;
        #pragma unroll
        for (int r = 0; r < 4; ++r) {
            const int off = bk4[r] * H + ci;
            float h0 = asel[g][r] + t4[r] * tw0[off] + b0[off];
            qp[r] += fmaxf(h0, 0.0f) * W1[off];
        }
    }
    #pragma unroll
    for (int r = 0; r < 4; ++r) {
        float s = qp[r];
        s += __shfl_xor(s, 1); s += __shfl_xor(s, 2);
        s += __shfl_xor(s, 4); s += __shfl_xor(s, 8);
        const int h = bk4[r];
        qp[r] = s + t4[r] * tw1[h] + b1[h];
    }
    if (cl == 0) {
        floatx4 Qv = { qp[0], qp[1], qp[2], qp[3] };
        *(floatx4*)(outq + rowbase + 4 * q) = Qv;
    }
}

extern "C" void kernel_launch(void* const* d_in, const int* in_sizes, int n_in,
                              void* d_out, int out_size, void* d_ws, size_t ws_size,
                              hipStream_t stream) {
    const float* dosage = (const float*)d_in[0];
    const float* x      = (const float*)d_in[1];
    const float* dW0    = (const float*)d_in[2];
    const float* db0    = (const float*)d_in[3];
    const float* dW1    = (const float*)d_in[4];
    const float* db1    = (const float*)d_in[5];
    const float* dbW    = (const float*)d_in[6];
    const float* dbB    = (const float*)d_in[7];
    const float* W0     = (const float*)d_in[8];
    const float* tw0    = (const float*)d_in[9];
    const float* b0     = (const float*)d_in[10];
    const float* W1     = (const float*)d_in[11];
    const float* tw1    = (const float*)d_in[12];
    const float* b1     = (const float*)d_in[13];

    const int Btot = in_sizes[0];
    float* outg = (float*)d_out;
    float* outq = outg + Btot;
    unsigned short* ws = (unsigned short*)d_ws;

    pack_kernel<<<NF_TOT, 64, 0, stream>>>(dW0, dW1, dbW, W0, ws);
    drnet_mfma<<<Btot / MWG, 256, 0, stream>>>(dosage, x, db0, db1, dbB,
                                               tw0, b0, W1, tw1, b1,
                                               ws, outg, outq);
}

// Round 5
// 203.229 us; speedup vs baseline: 1.1287x; 1.0351x over previous
//
#include <hip/hip_runtime.h>

typedef __attribute__((ext_vector_type(8))) short  short8;
typedef __attribute__((ext_vector_type(4))) float  floatx4;
typedef __attribute__((ext_vector_type(4))) int    intx4;

constexpr int DIN = 100;
constexpr int H   = 64;
constexpr int G   = 10;
constexpr int NH  = 5;
constexpr int MWG = 128;                 // rows per block (4 waves x 32 rows)
constexpr int HP  = 72;                  // hbuf pitch in halfwords: 144B rows, 16B-aligned

// fragment counts in ws: dW0 (K=128 padded) 16; dW1 8; dbW 2; W0 5h*8=40
constexpr int NF_DW0 = 16, NF_DW1 = 8, NF_DBW = 2;
constexpr int NF_LIN = NF_DW0 + NF_DW1 + NF_DBW;     // 26
constexpr int NF_TOT = NF_LIN + 40;                  // 66

__device__ __forceinline__ unsigned short f2bf_rne(float f) {
    union { float f; unsigned u; } v{f};
    unsigned r = v.u + 0x7FFF + ((v.u >> 16) & 1);   // RNE
    return (unsigned short)(r >> 16);
}

// round-half-up pack of 8 floats -> short8 (bf16)
__device__ __forceinline__ short8 pack8(const float* f) {
    intx4 p;
    #pragma unroll
    for (int j = 0; j < 4; ++j) {
        unsigned a = __float_as_uint(f[2 * j])     + 0x8000u;
        unsigned b = __float_as_uint(f[2 * j + 1]) + 0x8000u;
        p[j] = (int)((b & 0xFFFF0000u) | (a >> 16));
    }
    union { intx4 i; short8 s; } u; u.i = p;
    return u.s;
}

__device__ __forceinline__ unsigned short f2bf_hu(float f) {
    return (unsigned short)((__float_as_uint(f) + 0x8000u) >> 16);
}

__device__ __forceinline__ short8 ldfrag(const unsigned short* __restrict__ ws,
                                         int f, int lane) {
    return *(const short8*)(ws + (size_t)(f * 64 + lane) * 8);
}

// ---- pre-kernel: pack all weights as bf16 MFMA B-fragments into ws ----
// B-frag layout (16x16x32): lane holds B[k = (lane>>4)*8 + j][n = lane&15]
__global__ __launch_bounds__(64) void pack_kernel(
    const float* __restrict__ dW0, const float* __restrict__ dW1,
    const float* __restrict__ dbW, const float* __restrict__ W0,
    unsigned short* __restrict__ ws)
{
    const int f = blockIdx.x;            // fragment id 0..65
    const int lane = threadIdx.x;
    const int q = lane >> 4, cl = lane & 15;
    float v[8];
    if (f < NF_DW0) {                    // dW0: K padded 100->128 with zeros
        int c = f >> 2, g = f & 3;
        #pragma unroll
        for (int j = 0; j < 8; ++j) {
            int k = c * 32 + q * 8 + j, n = g * 16 + cl;
            v[j] = (k < DIN) ? dW0[k * H + n] : 0.0f;
        }
    } else if (f < NF_DW0 + NF_DW1) {    // dW1: K=64
        int r = f - NF_DW0; int c = r >> 2, g = r & 3;
        #pragma unroll
        for (int j = 0; j < 8; ++j) {
            int k = c * 32 + q * 8 + j, n = g * 16 + cl;
            v[j] = dW1[k * H + n];
        }
    } else if (f < NF_LIN) {             // dbW: K=64, N=11 padded to 16
        int c = f - (NF_DW0 + NF_DW1);
        #pragma unroll
        for (int j = 0; j < 8; ++j) {
            int k = c * 32 + q * 8 + j, n = cl;
            v[j] = (n <= G) ? dbW[k * (G + 1) + n] : 0.0f;
        }
    } else {                             // W0: 5 heads, K=64
        int r = f - NF_LIN; int h = r >> 3; r &= 7; int c = r >> 2, g = r & 3;
        #pragma unroll
        for (int j = 0; j < 8; ++j) {
            int k = c * 32 + q * 8 + j, n = g * 16 + cl;
            v[j] = W0[(h * H + k) * H + n];
        }
    }
    short8 s;
    #pragma unroll
    for (int j = 0; j < 8; ++j) s[j] = (short)f2bf_rne(v[j]);
    *(short8*)(ws + (size_t)(f * 64 + lane) * 8) = s;
}

// ---- main kernel: 32 rows/wave (2 m-tiles, shared frag loads), no barriers ----
__global__ __launch_bounds__(256, 4) void drnet_mfma(
    const float* __restrict__ dosage, const float* __restrict__ x,
    const float* __restrict__ db0, const float* __restrict__ db1,
    const float* __restrict__ dbB,
    const float* __restrict__ tw0, const float* __restrict__ b0,
    const float* __restrict__ W1, const float* __restrict__ tw1,
    const float* __restrict__ b1,
    const unsigned short* __restrict__ wsfrag,
    float* __restrict__ outg, float* __restrict__ outq)
{
    __shared__ unsigned short hbuf[MWG * HP];    // 18432 B
    const int tid  = threadIdx.x;
    const int wave = tid >> 6, lane = tid & 63;
    const int q = lane >> 4, cl = lane & 15;
    const int rowbase = blockIdx.x * MWG + wave * 32;   // this wave's 32 rows
    unsigned short* hb = hbuf + wave * 32 * HP;

    // dosage for my 8 C-layout rows: rows mt*16 + 4q + r (contiguous float4)
    float t8[2][4];
    int   bk8[2][4];
    #pragma unroll
    for (int mt = 0; mt < 2; ++mt) {
        floatx4 tv = *(const floatx4*)(dosage + rowbase + mt * 16 + 4 * q);
        #pragma unroll
        for (int r = 0; r < 4; ++r) {
            float t = tv[r];
            t8[mt][r] = t;
            int bk = (int)floorf(t * (float)NH);
            bk8[mt][r] = min(max(bk, 0), NH - 1);
        }
    }

    floatx4 acc[2][4];

    // ================= layer 1: h1 = relu(x @ dW0 + db0) =================
    {
        short8 a1[2][4];
        #pragma unroll
        for (int mt = 0; mt < 2; ++mt) {
            const float* xr = x + (size_t)(rowbase + mt * 16 + cl) * DIN;
            #pragma unroll
            for (int cch = 0; cch < 4; ++cch) {
                float f[8];
                if (cch < 3) {
                    floatx4 u0 = *(const floatx4*)(xr + cch * 32 + q * 8);
                    floatx4 u1 = *(const floatx4*)(xr + cch * 32 + q * 8 + 4);
                    f[0]=u0.x; f[1]=u0.y; f[2]=u0.z; f[3]=u0.w;
                    f[4]=u1.x; f[5]=u1.y; f[6]=u1.z; f[7]=u1.w;
                } else {
                    if (q == 0) {
                        floatx4 u0 = *(const floatx4*)(xr + 96);
                        f[0]=u0.x; f[1]=u0.y; f[2]=u0.z; f[3]=u0.w;
                        f[4]=f[5]=f[6]=f[7]=0.0f;
                    } else {
                        #pragma unroll
                        for (int j = 0; j < 8; ++j) f[j] = 0.0f;
                    }
                }
                a1[mt][cch] = pack8(f);
            }
        }
        #pragma unroll
        for (int mt = 0; mt < 2; ++mt)
            #pragma unroll
            for (int g = 0; g < 4; ++g) acc[mt][g] = (floatx4)0.0f;
        #pragma unroll
        for (int cch = 0; cch < 4; ++cch)
            #pragma unroll
            for (int g = 0; g < 4; ++g) {
                short8 bf = ldfrag(wsfrag, cch * 4 + g, lane);
                #pragma unroll
                for (int mt = 0; mt < 2; ++mt)
                    acc[mt][g] = __builtin_amdgcn_mfma_f32_16x16x32_bf16(a1[mt][cch], bf, acc[mt][g], 0, 0, 0);
            }
    }
    #pragma unroll
    for (int g = 0; g < 4; ++g) {
        float bias = db0[g * 16 + cl];
        #pragma unroll
        for (int mt = 0; mt < 2; ++mt)
            #pragma unroll
            for (int r = 0; r < 4; ++r)
                hb[(mt * 16 + 4 * q + r) * HP + g * 16 + cl] =
                    f2bf_hu(fmaxf(acc[mt][g][r] + bias, 0.0f));
    }
    // wave-private rows + in-order DS pipe: no barrier needed

    // ================= layer 2: h2 = relu(h1 @ dW1 + db1) =================
    {
        short8 a2[2][2];
        #pragma unroll
        for (int mt = 0; mt < 2; ++mt)
            #pragma unroll
            for (int cch = 0; cch < 2; ++cch)
                a2[mt][cch] = *(const short8*)(hb + (mt * 16 + cl) * HP + cch * 32 + q * 8);
        #pragma unroll
        for (int mt = 0; mt < 2; ++mt)
            #pragma unroll
            for (int g = 0; g < 4; ++g) acc[mt][g] = (floatx4)0.0f;
        #pragma unroll
        for (int cch = 0; cch < 2; ++cch)
            #pragma unroll
            for (int g = 0; g < 4; ++g) {
                short8 bf = ldfrag(wsfrag, NF_DW0 + cch * 4 + g, lane);
                #pragma unroll
                for (int mt = 0; mt < 2; ++mt)
                    acc[mt][g] = __builtin_amdgcn_mfma_f32_16x16x32_bf16(a2[mt][cch], bf, acc[mt][g], 0, 0, 0);
            }
    }
    #pragma unroll
    for (int g = 0; g < 4; ++g) {
        float bias = db1[g * 16 + cl];
        #pragma unroll
        for (int mt = 0; mt < 2; ++mt)
            #pragma unroll
            for (int r = 0; r < 4; ++r)
                hb[(mt * 16 + 4 * q + r) * HP + g * 16 + cl] =
                    f2bf_hu(fmaxf(acc[mt][g][r] + bias, 0.0f));
    }

    // h2 A-fragments (reused by density + all heads)
    short8 af[2][2];
    #pragma unroll
    for (int mt = 0; mt < 2; ++mt)
        #pragma unroll
        for (int cch = 0; cch < 2; ++cch)
            af[mt][cch] = *(const short8*)(hb + (mt * 16 + cl) * HP + cch * 32 + q * 8);

    // ================= density: softmax(h2 @ dbW + dbB) + interp =================
    {
        floatx4 accd[2];
        accd[0] = (floatx4)0.0f; accd[1] = (floatx4)0.0f;
        #pragma unroll
        for (int cch = 0; cch < 2; ++cch) {
            short8 bf = ldfrag(wsfrag, NF_DW0 + NF_DW1 + cch, lane);
            #pragma unroll
            for (int mt = 0; mt < 2; ++mt)
                accd[mt] = __builtin_amdgcn_mfma_f32_16x16x32_bf16(af[mt][cch], bf, accd[mt], 0, 0, 0);
        }
        const float dbBv = (cl <= G) ? dbB[cl] : 0.0f;
        #pragma unroll
        for (int mt = 0; mt < 2; ++mt) {
            float gout[4];
            #pragma unroll
            for (int r = 0; r < 4; ++r) {
                float l = (cl <= G) ? (accd[mt][r] + dbBv) : -1e30f;
                float m = l;
                m = fmaxf(m, __shfl_xor(m, 1)); m = fmaxf(m, __shfl_xor(m, 2));
                m = fmaxf(m, __shfl_xor(m, 4)); m = fmaxf(m, __shfl_xor(m, 8));
                float e = __expf(l - m);
                float s = e;
                s += __shfl_xor(s, 1); s += __shfl_xor(s, 2);
                s += __shfl_xor(s, 4); s += __shfl_xor(s, 8);
                const float t  = t8[mt][r];
                const float tB = t * (float)G;
                const float U  = ceilf(tB);
                const float inter = 1.0f - (U - tB);
                int Ui = (int)U; int Li = Ui - 1; if (Li < 0) Li = 0;
                float pL = __shfl(e, q * 16 + Li);
                float pU = __shfl(e, q * 16 + Ui);
                gout[r] = (pL + (pU - pL) * inter) / s;
            }
            if (cl == 0) {
                floatx4 gv = { gout[0], gout[1], gout[2], gout[3] };
                *(floatx4*)(outg + rowbase + mt * 16 + 4 * q) = gv;
            }
        }
    }

    // ===== heads: MFMA all 5; predicated accumulate (no asel array) =====
    float qp[2][4] = {{0,0,0,0},{0,0,0,0}};
    #pragma unroll 1
    for (int h = 0; h < NH; ++h) {
        floatx4 acch[2][4];
        #pragma unroll
        for (int mt = 0; mt < 2; ++mt)
            #pragma unroll
            for (int g = 0; g < 4; ++g) acch[mt][g] = (floatx4)0.0f;
        #pragma unroll
        for (int cch = 0; cch < 2; ++cch)
            #pragma unroll
            for (int g = 0; g < 4; ++g) {
                short8 bf = ldfrag(wsfrag, NF_LIN + h * 8 + cch * 4 + g, lane);
                #pragma unroll
                for (int mt = 0; mt < 2; ++mt)
                    acch[mt][g] = __builtin_amdgcn_mfma_f32_16x16x32_bf16(af[mt][cch], bf, acch[mt][g], 0, 0, 0);
            }
        // per-h coalesced epilogue params (lane reads h*H + g*16 + cl)
        float tw0g[4], b0g[4], w1g[4];
        #pragma unroll
        for (int g = 0; g < 4; ++g) {
            const int off = h * H + g * 16 + cl;
            tw0g[g] = tw0[off]; b0g[g] = b0[off]; w1g[g] = W1[off];
        }
        #pragma unroll
        for (int mt = 0; mt < 2; ++mt)
            #pragma unroll
            for (int r = 0; r < 4; ++r) {
                float s = 0.0f;
                #pragma unroll
                for (int g = 0; g < 4; ++g) {
                    float h0 = acch[mt][g][r] + t8[mt][r] * tw0g[g] + b0g[g];
                    s += fmaxf(h0, 0.0f) * w1g[g];
                }
                qp[mt][r] += (bk8[mt][r] == h) ? s : 0.0f;
            }
    }
    #pragma unroll
    for (int mt = 0; mt < 2; ++mt) {
        #pragma unroll
        for (int r = 0; r < 4; ++r) {
            float s = qp[mt][r];
            s += __shfl_xor(s, 1); s += __shfl_xor(s, 2);
            s += __shfl_xor(s, 4); s += __shfl_xor(s, 8);
            const int h = bk8[mt][r];
            qp[mt][r] = s + t8[mt][r] * tw1[h] + b1[h];
        }
        if (cl == 0) {
            floatx4 Qv = { qp[mt][0], qp[mt][1], qp[mt][2], qp[mt][3] };
            *(floatx4*)(outq + rowbase + mt * 16 + 4 * q) = Qv;
        }
    }
}

extern "C" void kernel_launch(void* const* d_in, const int* in_sizes, int n_in,
                              void* d_out, int out_size, void* d_ws, size_t ws_size,
                              hipStream_t stream) {
    const float* dosage = (const float*)d_in[0];
    const float* x      = (const float*)d_in[1];
    const float* dW0    = (const float*)d_in[2];
    const float* db0    = (const float*)d_in[3];
    const float* dW1    = (const float*)d_in[4];
    const float* db1    = (const float*)d_in[5];
    const float* dbW    = (const float*)d_in[6];
    const float* dbB    = (const float*)d_in[7];
    const float* W0     = (const float*)d_in[8];
    const float* tw0    = (const float*)d_in[9];
    const float* b0     = (const float*)d_in[10];
    const float* W1     = (const float*)d_in[11];
    const float* tw1    = (const float*)d_in[12];
    const float* b1     = (const float*)d_in[13];

    const int Btot = in_sizes[0];
    float* outg = (float*)d_out;
    float* outq = outg + Btot;
    unsigned short* ws = (unsigned short*)d_ws;

    pack_kernel<<<NF_TOT, 64, 0, stream>>>(dW0, dW1, dbW, W0, ws);
    drnet_mfma<<<Btot / MWG, 256, 0, stream>>>(dosage, x, db0, db1, dbB,
                                               tw0, b0, W1, tw1, b1,
                                               ws, outg, outq);
}

// Round 6
// 201.470 us; speedup vs baseline: 1.1386x; 1.0087x over previous
//
#include <hip/hip_runtime.h>

typedef __attribute__((ext_vector_type(8))) short  short8;
typedef __attribute__((ext_vector_type(4))) float  floatx4;
typedef __attribute__((ext_vector_type(4))) int    intx4;

constexpr int DIN = 100;
constexpr int H   = 64;
constexpr int G   = 10;
constexpr int NH  = 5;
constexpr int MWG = 128;                 // rows per block (4 waves x 32 rows)
constexpr int HP  = 72;                  // hbuf pitch in halfwords: 144B rows, 16B-aligned

// fragment counts in ws: dW0 (K=128 padded) 16; dW1 8; dbW 2; W0 5h*8=40
constexpr int NF_DW0 = 16, NF_DW1 = 8, NF_DBW = 2;
constexpr int NF_LIN = NF_DW0 + NF_DW1 + NF_DBW;     // 26
constexpr int NF_TOT = NF_LIN + 40;                  // 66

__device__ __forceinline__ unsigned short f2bf_rne(float f) {
    union { float f; unsigned u; } v{f};
    unsigned r = v.u + 0x7FFF + ((v.u >> 16) & 1);   // RNE
    return (unsigned short)(r >> 16);
}

// round-half-up pack of 8 floats -> short8 (bf16)
__device__ __forceinline__ short8 pack8(const float* f) {
    intx4 p;
    #pragma unroll
    for (int j = 0; j < 4; ++j) {
        unsigned a = __float_as_uint(f[2 * j])     + 0x8000u;
        unsigned b = __float_as_uint(f[2 * j + 1]) + 0x8000u;
        p[j] = (int)((b & 0xFFFF0000u) | (a >> 16));
    }
    union { intx4 i; short8 s; } u; u.i = p;
    return u.s;
}

__device__ __forceinline__ unsigned short f2bf_hu(float f) {
    return (unsigned short)((__float_as_uint(f) + 0x8000u) >> 16);
}

__device__ __forceinline__ short8 ldfrag(const unsigned short* __restrict__ ws,
                                         int f, int lane) {
    return *(const short8*)(ws + (size_t)(f * 64 + lane) * 8);
}

// ---- pre-kernel: pack all weights as bf16 MFMA B-fragments into ws ----
// B-frag layout (16x16x32): lane holds B[k = (lane>>4)*8 + j][n = lane&15]
__global__ __launch_bounds__(64) void pack_kernel(
    const float* __restrict__ dW0, const float* __restrict__ dW1,
    const float* __restrict__ dbW, const float* __restrict__ W0,
    unsigned short* __restrict__ ws)
{
    const int f = blockIdx.x;            // fragment id 0..65
    const int lane = threadIdx.x;
    const int q = lane >> 4, cl = lane & 15;
    float v[8];
    if (f < NF_DW0) {                    // dW0: K padded 100->128 with zeros
        int c = f >> 2, g = f & 3;
        #pragma unroll
        for (int j = 0; j < 8; ++j) {
            int k = c * 32 + q * 8 + j, n = g * 16 + cl;
            v[j] = (k < DIN) ? dW0[k * H + n] : 0.0f;
        }
    } else if (f < NF_DW0 + NF_DW1) {    // dW1: K=64
        int r = f - NF_DW0; int c = r >> 2, g = r & 3;
        #pragma unroll
        for (int j = 0; j < 8; ++j) {
            int k = c * 32 + q * 8 + j, n = g * 16 + cl;
            v[j] = dW1[k * H + n];
        }
    } else if (f < NF_LIN) {             // dbW: K=64, N=11 padded to 16
        int c = f - (NF_DW0 + NF_DW1);
        #pragma unroll
        for (int j = 0; j < 8; ++j) {
            int k = c * 32 + q * 8 + j, n = cl;
            v[j] = (n <= G) ? dbW[k * (G + 1) + n] : 0.0f;
        }
    } else {                             // W0: 5 heads, K=64
        int r = f - NF_LIN; int h = r >> 3; r &= 7; int c = r >> 2, g = r & 3;
        #pragma unroll
        for (int j = 0; j < 8; ++j) {
            int k = c * 32 + q * 8 + j, n = g * 16 + cl;
            v[j] = W0[(h * H + k) * H + n];
        }
    }
    short8 s;
    #pragma unroll
    for (int j = 0; j < 8; ++j) s[j] = (short)f2bf_rne(v[j]);
    *(short8*)(ws + (size_t)(f * 64 + lane) * 8) = s;
}

// ---- main kernel: 32 rows/wave; mt-split matmuls to cap live regs <=128 ----
__global__ __launch_bounds__(256, 4) void drnet_mfma(
    const float* __restrict__ dosage, const float* __restrict__ x,
    const float* __restrict__ db0, const float* __restrict__ db1,
    const float* __restrict__ dbB,
    const float* __restrict__ tw0, const float* __restrict__ b0,
    const float* __restrict__ W1, const float* __restrict__ tw1,
    const float* __restrict__ b1,
    const unsigned short* __restrict__ wsfrag,
    float* __restrict__ outg, float* __restrict__ outq)
{
    __shared__ unsigned short hbuf[MWG * HP];    // 18432 B
    const int tid  = threadIdx.x;
    const int wave = tid >> 6, lane = tid & 63;
    const int q = lane >> 4, cl = lane & 15;
    const int rowbase = blockIdx.x * MWG + wave * 32;   // this wave's 32 rows
    unsigned short* hb = hbuf + wave * 32 * HP;

    // dosage for my 8 C-layout rows: rows mt*16 + 4q + r (contiguous float4)
    float t8[2][4];
    int   bk8[2][4];
    #pragma unroll
    for (int mt = 0; mt < 2; ++mt) {
        floatx4 tv = *(const floatx4*)(dosage + rowbase + mt * 16 + 4 * q);
        #pragma unroll
        for (int r = 0; r < 4; ++r) {
            float t = tv[r];
            t8[mt][r] = t;
            int bk = (int)floorf(t * (float)NH);
            bk8[mt][r] = min(max(bk, 0), NH - 1);
        }
    }

    // ================= layer 1: h1 = relu(x @ dW0 + db0), mt-split =================
    #pragma unroll 1
    for (int mt = 0; mt < 2; ++mt) {
        short8 a1[4];
        const float* xr = x + (size_t)(rowbase + mt * 16 + cl) * DIN;
        #pragma unroll
        for (int cch = 0; cch < 4; ++cch) {
            float f[8];
            if (cch < 3) {
                floatx4 u0 = *(const floatx4*)(xr + cch * 32 + q * 8);
                floatx4 u1 = *(const floatx4*)(xr + cch * 32 + q * 8 + 4);
                f[0]=u0.x; f[1]=u0.y; f[2]=u0.z; f[3]=u0.w;
                f[4]=u1.x; f[5]=u1.y; f[6]=u1.z; f[7]=u1.w;
            } else {
                if (q == 0) {
                    floatx4 u0 = *(const floatx4*)(xr + 96);
                    f[0]=u0.x; f[1]=u0.y; f[2]=u0.z; f[3]=u0.w;
                    f[4]=f[5]=f[6]=f[7]=0.0f;
                } else {
                    #pragma unroll
                    for (int j = 0; j < 8; ++j) f[j] = 0.0f;
                }
            }
            a1[cch] = pack8(f);
        }
        floatx4 acc[4];
        #pragma unroll
        for (int g = 0; g < 4; ++g) acc[g] = (floatx4)0.0f;
        #pragma unroll
        for (int cch = 0; cch < 4; ++cch)
            #pragma unroll
            for (int g = 0; g < 4; ++g) {
                short8 bf = ldfrag(wsfrag, cch * 4 + g, lane);
                acc[g] = __builtin_amdgcn_mfma_f32_16x16x32_bf16(a1[cch], bf, acc[g], 0, 0, 0);
            }
        #pragma unroll
        for (int g = 0; g < 4; ++g) {
            float bias = db0[g * 16 + cl];
            #pragma unroll
            for (int r = 0; r < 4; ++r)
                hb[(mt * 16 + 4 * q + r) * HP + g * 16 + cl] =
                    f2bf_hu(fmaxf(acc[g][r] + bias, 0.0f));
        }
    }
    // wave-private rows + in-order DS pipe: no barrier needed

    // ================= layer 2: h2 = relu(h1 @ dW1 + db1), mt-split =================
    #pragma unroll 1
    for (int mt = 0; mt < 2; ++mt) {
        short8 a2[2];
        #pragma unroll
        for (int cch = 0; cch < 2; ++cch)
            a2[cch] = *(const short8*)(hb + (mt * 16 + cl) * HP + cch * 32 + q * 8);
        floatx4 acc[4];
        #pragma unroll
        for (int g = 0; g < 4; ++g) acc[g] = (floatx4)0.0f;
        #pragma unroll
        for (int cch = 0; cch < 2; ++cch)
            #pragma unroll
            for (int g = 0; g < 4; ++g) {
                short8 bf = ldfrag(wsfrag, NF_DW0 + cch * 4 + g, lane);
                acc[g] = __builtin_amdgcn_mfma_f32_16x16x32_bf16(a2[cch], bf, acc[g], 0, 0, 0);
            }
        #pragma unroll
        for (int g = 0; g < 4; ++g) {
            float bias = db1[g * 16 + cl];
            #pragma unroll
            for (int r = 0; r < 4; ++r)
                hb[(mt * 16 + 4 * q + r) * HP + g * 16 + cl] =
                    f2bf_hu(fmaxf(acc[g][r] + bias, 0.0f));
        }
    }

    // h2 A-fragments (reused by density + all heads)
    short8 af[2][2];
    #pragma unroll
    for (int mt = 0; mt < 2; ++mt)
        #pragma unroll
        for (int cch = 0; cch < 2; ++cch)
            af[mt][cch] = *(const short8*)(hb + (mt * 16 + cl) * HP + cch * 32 + q * 8);

    // ======= density: softmax(h2 @ dbW + dbB) + interp (no max-sub: logits tiny) =======
    {
        floatx4 accd[2];
        accd[0] = (floatx4)0.0f; accd[1] = (floatx4)0.0f;
        #pragma unroll
        for (int cch = 0; cch < 2; ++cch) {
            short8 bf = ldfrag(wsfrag, NF_DW0 + NF_DW1 + cch, lane);
            #pragma unroll
            for (int mt = 0; mt < 2; ++mt)
                accd[mt] = __builtin_amdgcn_mfma_f32_16x16x32_bf16(af[mt][cch], bf, accd[mt], 0, 0, 0);
        }
        const float dbBv = (cl <= G) ? dbB[cl] : 0.0f;
        #pragma unroll
        for (int mt = 0; mt < 2; ++mt) {
            float gout[4];
            #pragma unroll
            for (int r = 0; r < 4; ++r) {
                float e = (cl <= G) ? __expf(accd[mt][r] + dbBv) : 0.0f;
                float s = e;
                s += __shfl_xor(s, 1); s += __shfl_xor(s, 2);
                s += __shfl_xor(s, 4); s += __shfl_xor(s, 8);
                const float t  = t8[mt][r];
                const float tB = t * (float)G;
                const float U  = ceilf(tB);
                const float inter = 1.0f - (U - tB);
                int Ui = (int)U; int Li = Ui - 1; if (Li < 0) Li = 0;
                float pL = __shfl(e, q * 16 + Li);
                float pU = __shfl(e, q * 16 + Ui);
                gout[r] = (pL + (pU - pL) * inter) / s;
            }
            if (cl == 0) {
                floatx4 gv = { gout[0], gout[1], gout[2], gout[3] };
                *(floatx4*)(outg + rowbase + mt * 16 + 4 * q) = gv;
            }
        }
    }

    // ===== heads: MFMA all 5; g-half split (acch 16 regs); predicated accumulate =====
    float qp[2][4] = {{0,0,0,0},{0,0,0,0}};
    #pragma unroll 1
    for (int h = 0; h < NH; ++h) {
        #pragma unroll
        for (int gh = 0; gh < 2; ++gh) {
            floatx4 acch[2][2];
            #pragma unroll
            for (int mt = 0; mt < 2; ++mt)
                #pragma unroll
                for (int g = 0; g < 2; ++g) acch[mt][g] = (floatx4)0.0f;
            #pragma unroll
            for (int cch = 0; cch < 2; ++cch)
                #pragma unroll
                for (int g = 0; g < 2; ++g) {
                    short8 bf = ldfrag(wsfrag, NF_LIN + h * 8 + cch * 4 + gh * 2 + g, lane);
                    #pragma unroll
                    for (int mt = 0; mt < 2; ++mt)
                        acch[mt][g] = __builtin_amdgcn_mfma_f32_16x16x32_bf16(af[mt][cch], bf, acch[mt][g], 0, 0, 0);
                }
            #pragma unroll
            for (int g = 0; g < 2; ++g) {
                const int off = h * H + (gh * 2 + g) * 16 + cl;
                const float tw0v = tw0[off], b0v = b0[off], w1v = W1[off];
                #pragma unroll
                for (int mt = 0; mt < 2; ++mt)
                    #pragma unroll
                    for (int r = 0; r < 4; ++r) {
                        float h0 = acch[mt][g][r] + t8[mt][r] * tw0v + b0v;
                        float c  = fmaxf(h0, 0.0f) * w1v;
                        qp[mt][r] += (bk8[mt][r] == h) ? c : 0.0f;
                    }
            }
        }
    }
    #pragma unroll
    for (int mt = 0; mt < 2; ++mt) {
        #pragma unroll
        for (int r = 0; r < 4; ++r) {
            float s = qp[mt][r];
            s += __shfl_xor(s, 1); s += __shfl_xor(s, 2);
            s += __shfl_xor(s, 4); s += __shfl_xor(s, 8);
            const int h = bk8[mt][r];
            qp[mt][r] = s + t8[mt][r] * tw1[h] + b1[h];
        }
        if (cl == 0) {
            floatx4 Qv = { qp[mt][0], qp[mt][1], qp[mt][2], qp[mt][3] };
            *(floatx4*)(outq + rowbase + mt * 16 + 4 * q) = Qv;
        }
    }
}

extern "C" void kernel_launch(void* const* d_in, const int* in_sizes, int n_in,
                              void* d_out, int out_size, void* d_ws, size_t ws_size,
                              hipStream_t stream) {
    const float* dosage = (const float*)d_in[0];
    const float* x      = (const float*)d_in[1];
    const float* dW0    = (const float*)d_in[2];
    const float* db0    = (const float*)d_in[3];
    const float* dW1    = (const float*)d_in[4];
    const float* db1    = (const float*)d_in[5];
    const float* dbW    = (const float*)d_in[6];
    const float* dbB    = (const float*)d_in[7];
    const float* W0     = (const float*)d_in[8];
    const float* tw0    = (const float*)d_in[9];
    const float* b0     = (const float*)d_in[10];
    const float* W1     = (const float*)d_in[11];
    const float* tw1    = (const float*)d_in[12];
    const float* b1     = (const float*)d_in[13];

    const int Btot = in_sizes[0];
    float* outg = (float*)d_out;
    float* outq = outg + Btot;
    unsigned short* ws = (unsigned short*)d_ws;

    pack_kernel<<<NF_TOT, 64, 0, stream>>>(dW0, dW1, dbW, W0, ws);
    drnet_mfma<<<Btot / MWG, 256, 0, stream>>>(dosage, x, db0, db1, dbB,
                                               tw0, b0, W1, tw1, b1,
                                               ws, outg, outq);
}